// Round 9
// baseline (48.106 us; speedup 1.0000x reference)
//
#include <hip/hip_runtime.h>
#include <stdint.h>

typedef short bf16x8 __attribute__((ext_vector_type(8)));
typedef float f32x4 __attribute__((ext_vector_type(4)));

#define NCI 128
#define NCO 128
#define HIN 64
#define HP  66
#define NB  8

__device__ __forceinline__ unsigned short f32_to_bf16(float f) {
    union { float f; uint32_t u; } v; v.f = f;
    return (unsigned short)((v.u + 0x7FFFu + ((v.u >> 16) & 1u)) >> 16);
}

__device__ __forceinline__ void gl_lds16(const void* g, void* l) {
    __builtin_amdgcn_global_load_lds(
        (const __attribute__((address_space(1))) unsigned int*)g,
        (__attribute__((address_space(3))) unsigned int*)l, 16, 0, 0);
}

__device__ __forceinline__ void vmw0() {
    asm volatile("s_waitcnt vmcnt(0)" ::: "memory");
}
__device__ __forceinline__ void lkw0() {
    asm volatile("s_waitcnt lgkmcnt(0)" ::: "memory");
}
__device__ __forceinline__ void barx() {
    asm volatile("" ::: "memory");
    __builtin_amdgcn_s_barrier();
    asm volatile("" ::: "memory");
}

// Effective 2x2-tap weight for parity (py,px), tap (ty,tx)
__device__ __forceinline__ float weff_sum(const float* wp, int py, int px, int ty, int tx) {
    float s = 0.f;
    #pragma unroll
    for (int ky = 0; ky < 3; ++ky) {
        bool iy = (py == 0) ? (ty == 0 ? (ky == 0) : (ky >= 1))
                            : (ty == 0 ? (ky <= 1) : (ky == 2));
        if (!iy) continue;
        #pragma unroll
        for (int kx = 0; kx < 3; ++kx) {
            bool ix = (px == 0) ? (tx == 0 ? (kx == 0) : (kx >= 1))
                                : (tx == 0 ? (kx <= 1) : (kx == 2));
            if (ix) s += wp[ky * 3 + kx];
        }
    }
    return s;
}

// ---- fused prologue ----
// blocks [0,1024): Weff -> Aw5, wave-fragment-major, 64co bands (wm):
//   offset = ((par*16+kt)*2 + wm)*2048 + f*512 + pl*128 + rl*8 + e
//   content = Weff[par][co = wm*64+f*16+rl][k = kt*32+pl*8+e]   (512 KB)
// blocks [1024,1552): x [8][128][64][64] f32 -> xq [8][4][66][66][32] bf16
//   (ci-chunked NHWC, halo written here).
__global__ __launch_bounds__(256) void prep_kernel(
        const float* __restrict__ W, const float* __restrict__ x,
        unsigned short* __restrict__ Aw5, unsigned short* __restrict__ xq) {
    if (blockIdx.x < 1024) {
        int idx = blockIdx.x * 256 + threadIdx.x;     // 262144 total
        int e   = idx & 7;
        int rl  = (idx >> 3) & 15;
        int pl  = (idx >> 7) & 3;
        int f   = (idx >> 9) & 3;
        int wm  = (idx >> 11) & 1;
        int kt  = (idx >> 12) & 15;
        int par = idx >> 16;
        int co = wm * 64 + f * 16 + rl;
        int k  = kt * 32 + pl * 8 + e;
        int tap = k >> 7, ci = k & 127;
        Aw5[idx] = f32_to_bf16(weff_sum(W + (co * NCI + ci) * 9,
                                        par >> 1, par & 1, tap >> 1, tap & 1));
    } else {
        const int bb = blockIdx.x - 1024;             // 528 blocks
        const int b = bb / HP, hp = bb % HP;
        const int t = threadIdx.x;
        if (hp == 0 || hp == HP - 1) {
            bf16x8 z = (bf16x8){0, 0, 0, 0, 0, 0, 0, 0};
            for (int i = t; i < 4 * HP * 4; i += 256) {
                int g = i / (HP * 4), rem = i % (HP * 4);
                unsigned short* dst = xq +
                    ((((size_t)(b * 4 + g) * HP + hp) * HP) << 5) + rem * 8;
                *(bf16x8*)dst = z;
            }
            return;
        }
        const int h = hp - 1;
        if (t < 32) {                                  // column halo wp = 0, 65
            bf16x8 z = (bf16x8){0, 0, 0, 0, 0, 0, 0, 0};
            int g = t >> 3, wpc = ((t >> 2) & 1) * (HP - 1), q = t & 3;
            unsigned short* dst = xq +
                ((((size_t)(b * 4 + g) * HP + hp) * HP + wpc) << 5) + q * 8;
            *(bf16x8*)dst = z;
        }
        const int w = t & 63, g = t >> 6;
        const float* src = x + ((size_t)(b * NCI + g * 32) * (HIN * HIN)) + h * HIN + w;
        unsigned short* dst = xq +
            ((((size_t)(b * 4 + g) * HP + hp) * HP + (w + 1)) << 5);
        #pragma unroll
        for (int q = 0; q < 4; ++q) {
            bf16x8 v;
            #pragma unroll
            for (int j = 0; j < 8; ++j)
                v[j] = (short)f32_to_bf16(src[(size_t)(q * 8 + j) * (HIN * HIN)]);
            *(bf16x8*)(dst + q * 8) = v;
        }
    }
}

// Main GEMM: barrier-free K-loop, balanced 64co x 64sp wave tiles.
// B (3x66x128ci = 50.7 KB) staged to LDS ONCE; A streams global(L2)->reg,
// 1-ahead ping-pong. 8 waves = pxw(2) x wm(2) x wn(2). 2 blocks/CU target.
__global__ __launch_bounds__(512, 4) void upconv10_kernel(
        const unsigned short* __restrict__ xq, const unsigned short* __restrict__ Aw5,
        const float* __restrict__ bv, float* __restrict__ out) {
    __shared__ __align__(16) unsigned short smem[25344];   // 50688 B
    const int d = blockIdx.x;
    const int dsw = (d & 7) * 64 + (d >> 3);     // bijective XCD chunk swizzle
    const int tile = dsw >> 1, py = dsw & 1;
    const int bi = tile >> 5;
    const int oy0 = (tile & 31) * 2;
    const int tid = threadIdx.x, lane = tid & 63, wv = tid >> 6;
    const int pxw = wv & 1, wm = (wv >> 1) & 1, wn = wv >> 2;
    const int rl = lane & 15, pl = lane >> 4;
    const int par = py * 2 + pxw;

    // ---- stage B once: slot dd -> (cell = dd>>4, chunk' = dd&15),
    //      chunk = chunk' ^ (col&15)  (bank swizzle; linear LDS dest)
    #pragma unroll
    for (int i = 0; i < 7; ++i) {
        int dd = i * 512 + tid;
        if (dd < 3168) {
            int cell = dd >> 4, chq = dd & 15;
            int ry = cell / 66, colg = cell - ry * 66;
            int chunk = chq ^ (colg & 15);
            const unsigned short* gb = xq +
                ((((size_t)(bi * 4 + (chunk >> 2)) * HP + (oy0 + py + ry)) * HP + colg) << 5)
                + (chunk & 3) * 8;
            gl_lds16(gb, &smem[dd * 8]);
        }
    }

    f32x4 acc[4][4];
    #pragma unroll
    for (int i = 0; i < 4; ++i)
        #pragma unroll
        for (int j = 0; j < 4; ++j)
            acc[i][j] = (f32x4){0.f, 0.f, 0.f, 0.f};

    bf16x8 A0[4], A1[4];
    auto loadA = [&](bf16x8* Ad, int kt2) {
        const unsigned short* p = Aw5 + (((par * 16 + kt2) * 2 + wm) << 11) + lane * 8;
        #pragma unroll
        for (int f = 0; f < 4; ++f)
            Ad[f] = *(const bf16x8*)(p + f * 512);
    };

    loadA(A0, 0);
    vmw0();        // B staged + A0 ready
    barx();        // the ONLY pre-epilogue barrier

    #pragma unroll 2
    for (int kt = 0; kt < 16; ++kt) {
        if (kt < 15) loadA((kt & 1) ? A0 : A1, kt + 1);
        const bf16x8* Ac = (kt & 1) ? A1 : A0;
        const int ty = kt >> 3, tx = (kt >> 2) & 1, cq = kt & 3;
        const int ry = wn + ty;
        __builtin_amdgcn_s_setprio(1);
        #pragma unroll
        for (int f = 0; f < 4; ++f) {
            const int colg = f * 16 + rl + pxw + tx;
            const int chq = (cq * 4 + pl) ^ (colg & 15);
            bf16x8 bfr = *(const bf16x8*)&smem[(((ry * 66 + colg) << 4) + chq) * 8];
            #pragma unroll
            for (int fm = 0; fm < 4; ++fm)
                acc[fm][f] = __builtin_amdgcn_mfma_f32_16x16x32_bf16(
                    Ac[fm], bfr, acc[fm][f], 0, 0, 0);
        }
        __builtin_amdgcn_s_setprio(0);
    }

    barx();   // all waves done reading B before lf overwrite

    // coalesced epilogue via LDS: lf[co_l 0..31][r 0..1][xx 0..127], stride 264
    float* lf = (float*)smem;
    const int co_l = tid >> 4;
    const int rem = tid & 15, rr = rem >> 3, x16 = (rem & 7) * 16;
    const int co_g = (co_l >> 4) * 64 + (co_l & 15);
    const int yy = 2 * (oy0 + rr) + py;

    #pragma unroll
    for (int fm = 0; fm < 4; ++fm) {
        #pragma unroll
        for (int fn = 0; fn < 4; ++fn) {
            int n = wn * 64 + fn * 16 + rl;
            int r = n >> 6, xx = 2 * (n & 63) + pxw;
            #pragma unroll
            for (int j = 0; j < 4; ++j) {
                int col = wm * 16 + pl * 4 + j;
                lf[col * 264 + r * 132 + xx] = acc[fm][fn][j];
            }
        }
        lkw0();
        barx();
        const int co = co_g + fm * 16;
        const float bb = bv[co];
        float* op = out + (((size_t)bi * NCO + co) * 128 + yy) * 128 + x16;
        const float* sp = lf + co_l * 264 + rr * 132 + x16;
        #pragma unroll
        for (int q = 0; q < 4; ++q) {
            f32x4 v = *(const f32x4*)(sp + q * 4);
            v[0] += bb; v[1] += bb; v[2] += bb; v[3] += bb;
            *(f32x4*)(op + q * 4) = v;
        }
        if (fm < 3) barx();
    }
}

// -------- fallback (ws too small for xq): flat Weff + direct-x kernel --------
__global__ void weff_flat_kernel(const float* __restrict__ W,
                                 unsigned short* __restrict__ Aw) {
    int idx = blockIdx.x * 256 + threadIdx.x;   // Aw[par][co][512]
    int par = idx >> 16;
    int co  = (idx >> 9) & 127;
    int k   = idx & 511;
    int tap = k >> 7, ci = k & 127;
    Aw[idx] = f32_to_bf16(weff_sum(W + (co * NCI + ci) * 9,
                                   par >> 1, par & 1, tap >> 1, tap & 1));
}

__global__ __launch_bounds__(256) void upconv_fb_kernel(
        const float* __restrict__ x, const unsigned short* __restrict__ Aw,
        const float* __restrict__ bv, float* __restrict__ out) {
    __shared__ __align__(16) unsigned short A_lds[128 * 32];
    __shared__ __align__(16) unsigned short B_lds[128 * 32];
    const int par = blockIdx.y, py = par >> 1, px = par & 1;
    const int s0 = blockIdx.x * 128;
    const int bimg = s0 >> 12;
    const int oy0 = (s0 >> 6) & 63;
    const int tid = threadIdx.x;
    const int lane = tid & 63, wave = tid >> 6;
    const int wm = wave >> 1, wn = wave & 1;
    const float* xb = x + bimg * (NCI * HIN * HIN);
    f32x4 acc[4][4];
    #pragma unroll
    for (int i = 0; i < 4; ++i)
        #pragma unroll
        for (int j = 0; j < 4; ++j)
            acc[i][j] = (f32x4){0.f, 0.f, 0.f, 0.f};
    for (int kt = 0; kt < 16; ++kt) {
        const int tap = kt >> 2, ci0 = (kt & 3) * 32;
        const int ty = tap >> 1, tx = tap & 1;
        #pragma unroll
        for (int i = 0; i < 2; ++i) {
            int c = i * 256 + tid;
            *(bf16x8*)(&A_lds[c * 8]) = *(const bf16x8*)(Aw +
                ((par * 128 + (c >> 2)) * 512 + kt * 32 + (c & 3) * 8));
        }
        #pragma unroll
        for (int i = 0; i < 2; ++i) {
            int tsk = i * 256 + tid;
            int n = tsk & 127, kg = tsk >> 7;
            int r = n >> 6, ox = n & 63;
            int row = oy0 + r - 1 + py + ty;
            int col = ox - 1 + px + tx;
            bool ok = (row >= 0) & (row < HIN) & (col >= 0) & (col < HIN);
            const float* xp = xb + (((ci0 + kg * 8) * HIN + row) * HIN + col);
            bf16x8 v;
            #pragma unroll
            for (int q = 0; q < 8; ++q) {
                float f = ok ? xp[q * (HIN * HIN)] : 0.f;
                v[q] = (short)f32_to_bf16(f);
            }
            *(bf16x8*)(&B_lds[n * 32 + kg * 8]) = v;
        }
        __syncthreads();
        const int seg = (lane >> 4) * 8, rl2 = lane & 15;
        bf16x8 af[4], bfr[4];
        #pragma unroll
        for (int f = 0; f < 4; ++f)
            af[f] = *(const bf16x8*)(&A_lds[(wm * 64 + f * 16 + rl2) * 32 + seg]);
        #pragma unroll
        for (int f = 0; f < 4; ++f)
            bfr[f] = *(const bf16x8*)(&B_lds[(wn * 64 + f * 16 + rl2) * 32 + seg]);
        #pragma unroll
        for (int fm = 0; fm < 4; ++fm)
            #pragma unroll
            for (int fn = 0; fn < 4; ++fn)
                acc[fm][fn] = __builtin_amdgcn_mfma_f32_16x16x32_bf16(
                    af[fm], bfr[fn], acc[fm][fn], 0, 0, 0);
        __syncthreads();
    }
    #pragma unroll
    for (int fm = 0; fm < 4; ++fm) {
        const int co_b = wm * 64 + fm * 16 + (lane >> 4) * 4;
        float bias4[4];
        #pragma unroll
        for (int j = 0; j < 4; ++j) bias4[j] = bv[co_b + j];
        #pragma unroll
        for (int fn = 0; fn < 4; ++fn) {
            int n = wn * 64 + fn * 16 + (lane & 15);
            int s = s0 + n;
            int ox = s & 63, oy = (s >> 6) & 63, bi2 = s >> 12;
            int yy = 2 * oy + py, xx = 2 * ox + px;
            float* op = out + ((size_t)bi2 * 128 * 128 * 128) + (size_t)yy * 128 + xx;
            #pragma unroll
            for (int j = 0; j < 4; ++j)
                op[(size_t)(co_b + j) * (128 * 128)] = acc[fm][fn][j] + bias4[j];
        }
    }
}

extern "C" void kernel_launch(void* const* d_in, const int* in_sizes, int n_in,
                              void* d_out, int out_size, void* d_ws, size_t ws_size,
                              hipStream_t stream) {
    const float* x  = (const float*)d_in[0];
    const float* W  = (const float*)d_in[1];
    const float* bv = (const float*)d_in[2];
    float* out = (float*)d_out;
    unsigned short* Aw = (unsigned short*)d_ws;               // 512 KB
    const size_t aw_bytes = (size_t)4 * 16 * 2 * 2048 * sizeof(unsigned short);
    const size_t xq_bytes = (size_t)NB * 4 * HP * HP * 32 * sizeof(unsigned short);

    if (ws_size >= aw_bytes + xq_bytes) {
        unsigned short* xq = (unsigned short*)((char*)d_ws + aw_bytes);
        prep_kernel<<<1024 + NB * HP, 256, 0, stream>>>(W, x, Aw, xq);
        upconv10_kernel<<<512, 512, 0, stream>>>(xq, Aw, bv, out);
    } else {
        weff_flat_kernel<<<1024, 256, 0, stream>>>(W, Aw);
        upconv_fb_kernel<<<dim3(256, 4), 256, 0, stream>>>(x, Aw, bv, out);
    }
}

// Round 10
// 47.362 us; speedup vs baseline: 1.0157x; 1.0157x over previous
//
#include <hip/hip_runtime.h>
#include <stdint.h>

typedef short bf16x8 __attribute__((ext_vector_type(8)));
typedef float f32x4 __attribute__((ext_vector_type(4)));

#define NCI 128
#define NCO 128
#define HIN 64
#define HP  66
#define NB  8

__device__ __forceinline__ unsigned short f32_to_bf16(float f) {
    union { float f; uint32_t u; } v; v.f = f;
    return (unsigned short)((v.u + 0x7FFFu + ((v.u >> 16) & 1u)) >> 16);
}

__device__ __forceinline__ void gl_lds16(const void* g, void* l) {
    __builtin_amdgcn_global_load_lds(
        (const __attribute__((address_space(1))) unsigned int*)g,
        (__attribute__((address_space(3))) unsigned int*)l, 16, 0, 0);
}

__device__ __forceinline__ void vmw0() {
    asm volatile("s_waitcnt vmcnt(0)" ::: "memory");
}
__device__ __forceinline__ void lkw0() {
    asm volatile("s_waitcnt lgkmcnt(0)" ::: "memory");
}
__device__ __forceinline__ void barx() {
    asm volatile("" ::: "memory");
    __builtin_amdgcn_s_barrier();
    asm volatile("" ::: "memory");
}

// Effective 2x2-tap weight for parity (py,px), tap (ty,tx)
__device__ __forceinline__ float weff_sum(const float* wp, int py, int px, int ty, int tx) {
    float s = 0.f;
    #pragma unroll
    for (int ky = 0; ky < 3; ++ky) {
        bool iy = (py == 0) ? (ty == 0 ? (ky == 0) : (ky >= 1))
                            : (ty == 0 ? (ky <= 1) : (ky == 2));
        if (!iy) continue;
        #pragma unroll
        for (int kx = 0; kx < 3; ++kx) {
            bool ix = (px == 0) ? (tx == 0 ? (kx == 0) : (kx >= 1))
                                : (tx == 0 ? (kx <= 1) : (kx == 2));
            if (ix) s += wp[ky * 3 + kx];
        }
    }
    return s;
}

// ---- fused prologue ----
// blocks [0,1024): Weff -> Aw5, wave-fragment-major, 64co bands (wm):
//   offset = ((par*16+kt)*2 + wm)*2048 + f*512 + pl*128 + rl*8 + e
//   content = Weff[par][co = wm*64+f*16+rl][k = kt*32+pl*8+e]   (512 KB)
// blocks [1024,1552): x [8][128][64][64] f32 -> xq [8][4][66][66][32] bf16
//   (ci-chunked NHWC, halo written here).
__global__ __launch_bounds__(256) void prep_kernel(
        const float* __restrict__ W, const float* __restrict__ x,
        unsigned short* __restrict__ Aw5, unsigned short* __restrict__ xq) {
    if (blockIdx.x < 1024) {
        int idx = blockIdx.x * 256 + threadIdx.x;     // 262144 total
        int e   = idx & 7;
        int rl  = (idx >> 3) & 15;
        int pl  = (idx >> 7) & 3;
        int f   = (idx >> 9) & 3;
        int wm  = (idx >> 11) & 1;
        int kt  = (idx >> 12) & 15;
        int par = idx >> 16;
        int co = wm * 64 + f * 16 + rl;
        int k  = kt * 32 + pl * 8 + e;
        int tap = k >> 7, ci = k & 127;
        Aw5[idx] = f32_to_bf16(weff_sum(W + (co * NCI + ci) * 9,
                                        par >> 1, par & 1, tap >> 1, tap & 1));
    } else {
        const int bb = blockIdx.x - 1024;             // 528 blocks
        const int b = bb / HP, hp = bb % HP;
        const int t = threadIdx.x;
        if (hp == 0 || hp == HP - 1) {
            bf16x8 z = (bf16x8){0, 0, 0, 0, 0, 0, 0, 0};
            for (int i = t; i < 4 * HP * 4; i += 256) {
                int g = i / (HP * 4), rem = i % (HP * 4);
                unsigned short* dst = xq +
                    ((((size_t)(b * 4 + g) * HP + hp) * HP) << 5) + rem * 8;
                *(bf16x8*)dst = z;
            }
            return;
        }
        const int h = hp - 1;
        if (t < 32) {                                  // column halo wp = 0, 65
            bf16x8 z = (bf16x8){0, 0, 0, 0, 0, 0, 0, 0};
            int g = t >> 3, wpc = ((t >> 2) & 1) * (HP - 1), q = t & 3;
            unsigned short* dst = xq +
                ((((size_t)(b * 4 + g) * HP + hp) * HP + wpc) << 5) + q * 8;
            *(bf16x8*)dst = z;
        }
        const int w = t & 63, g = t >> 6;
        const float* src = x + ((size_t)(b * NCI + g * 32) * (HIN * HIN)) + h * HIN + w;
        unsigned short* dst = xq +
            ((((size_t)(b * 4 + g) * HP + hp) * HP + (w + 1)) << 5);
        #pragma unroll
        for (int q = 0; q < 4; ++q) {
            bf16x8 v;
            #pragma unroll
            for (int j = 0; j < 8; ++j)
                v[j] = (short)f32_to_bf16(src[(size_t)(q * 8 + j) * (HIN * HIN)]);
            *(bf16x8*)(dst + q * 8) = v;
        }
    }
}

// Main GEMM: barrier-free K-loop, 64co x 128sp wave tiles (A and B both
// dedup'd). B (3x66x128ci = 50.7 KB) staged to LDS ONCE; A streams
// global(L2)->reg 1-ahead. 256 thr = 4 waves: pxw(2) x wm(2). acc[4][8]
// = 128 AGPR. 2 blocks/CU: one block's store-drain overlaps the other's loop.
__global__ __launch_bounds__(256, 2) void upconv11_kernel(
        const unsigned short* __restrict__ xq, const unsigned short* __restrict__ Aw5,
        const float* __restrict__ bv, float* __restrict__ out) {
    __shared__ __align__(16) unsigned short smem[25344];   // 50688 B
    const int d = blockIdx.x;
    const int dsw = (d & 7) * 64 + (d >> 3);     // bijective XCD chunk swizzle
    const int tile = dsw >> 1, py = dsw & 1;
    const int bi = tile >> 5;
    const int oy0 = (tile & 31) * 2;
    const int tid = threadIdx.x, lane = tid & 63, wv = tid >> 6;
    const int pxw = wv & 1, wm = wv >> 1;
    const int rl = lane & 15, pl = lane >> 4;
    const int par = py * 2 + pxw;

    // ---- stage B once: slot dd -> (cell = dd>>4, chunk' = dd&15),
    //      chunk = chunk' ^ (col&15)  (bank swizzle; linear LDS dest)
    #pragma unroll
    for (int i = 0; i < 13; ++i) {
        int dd = i * 256 + tid;
        if (dd < 3168) {
            int cell = dd >> 4, chq = dd & 15;
            int ry = cell / 66, colg = cell - ry * 66;
            int chunk = chq ^ (colg & 15);
            const unsigned short* gb = xq +
                ((((size_t)(bi * 4 + (chunk >> 2)) * HP + (oy0 + py + ry)) * HP + colg) << 5)
                + (chunk & 3) * 8;
            gl_lds16(gb, &smem[dd * 8]);
        }
    }

    f32x4 acc[4][8];
    #pragma unroll
    for (int i = 0; i < 4; ++i)
        #pragma unroll
        for (int j = 0; j < 8; ++j)
            acc[i][j] = (f32x4){0.f, 0.f, 0.f, 0.f};

    bf16x8 A0[4], A1[4];
    auto loadA = [&](bf16x8* Ad, int kt2) {
        const unsigned short* p = Aw5 + (((par * 16 + kt2) * 2 + wm) << 11) + lane * 8;
        #pragma unroll
        for (int f = 0; f < 4; ++f)
            Ad[f] = *(const bf16x8*)(p + f * 512);
    };

    loadA(A0, 0);
    vmw0();        // B staged + A0 ready
    barx();        // the ONLY pre-epilogue barrier

    #pragma unroll 2
    for (int kt = 0; kt < 16; ++kt) {
        if (kt < 15) loadA((kt & 1) ? A0 : A1, kt + 1);
        const bf16x8* Ac = (kt & 1) ? A1 : A0;
        const int ty = kt >> 3, tx = (kt >> 2) & 1, cq = kt & 3;
        __builtin_amdgcn_s_setprio(1);
        #pragma unroll
        for (int f = 0; f < 8; ++f) {
            const int ry = (f >> 2) + ty;
            const int colg = (f & 3) * 16 + rl + pxw + tx;
            const int chq = (cq * 4 + pl) ^ (colg & 15);
            bf16x8 bfr = *(const bf16x8*)&smem[(((ry * 66 + colg) << 4) + chq) * 8];
            #pragma unroll
            for (int fm = 0; fm < 4; ++fm)
                acc[fm][f] = __builtin_amdgcn_mfma_f32_16x16x32_bf16(
                    Ac[fm], bfr, acc[fm][f], 0, 0, 0);
        }
        __builtin_amdgcn_s_setprio(0);
    }

    barx();   // all waves done reading B before lf overwrite

    // coalesced epilogue via LDS: lf[co_loc 0..31][r 0..1][xx 0..127], stride 264.
    // Round b (co band b*32): writers are waves with wm == b>>1, fm = (b&1)*2 + {0,1}.
    float* lf = (float*)smem;
    const int co_l = tid >> 3;
    const int rem = tid & 7, rr = rem >> 2, x32 = (rem & 3) * 32;
    const int yy = 2 * (oy0 + rr) + py;

    #pragma unroll
    for (int b = 0; b < 4; ++b) {
        if (wm == (b >> 1)) {
            const int fmb = (b & 1) * 2;
            #pragma unroll
            for (int f2 = 0; f2 < 2; ++f2) {
                const int fm = fmb + f2;
                #pragma unroll
                for (int fn = 0; fn < 8; ++fn) {
                    int n = fn * 16 + rl;
                    int r = n >> 6, xx = 2 * (n & 63) + pxw;
                    #pragma unroll
                    for (int j = 0; j < 4; ++j)
                        lf[(f2 * 16 + pl * 4 + j) * 264 + r * 132 + xx] = acc[fm][fn][j];
                }
            }
        }
        lkw0();
        barx();
        const int co = b * 32 + co_l;
        const float bb = bv[co];
        float* op = out + (((size_t)bi * NCO + co) * 128 + yy) * 128 + x32;
        const float* sp = lf + co_l * 264 + rr * 132 + x32;
        #pragma unroll
        for (int q = 0; q < 8; ++q) {
            f32x4 v = *(const f32x4*)(sp + q * 4);
            v[0] += bb; v[1] += bb; v[2] += bb; v[3] += bb;
            *(f32x4*)(op + q * 4) = v;
        }
        if (b < 3) barx();
    }
}

// -------- fallback (ws too small for xq): flat Weff + direct-x kernel --------
__global__ void weff_flat_kernel(const float* __restrict__ W,
                                 unsigned short* __restrict__ Aw) {
    int idx = blockIdx.x * 256 + threadIdx.x;   // Aw[par][co][512]
    int par = idx >> 16;
    int co  = (idx >> 9) & 127;
    int k   = idx & 511;
    int tap = k >> 7, ci = k & 127;
    Aw[idx] = f32_to_bf16(weff_sum(W + (co * NCI + ci) * 9,
                                   par >> 1, par & 1, tap >> 1, tap & 1));
}

__global__ __launch_bounds__(256) void upconv_fb_kernel(
        const float* __restrict__ x, const unsigned short* __restrict__ Aw,
        const float* __restrict__ bv, float* __restrict__ out) {
    __shared__ __align__(16) unsigned short A_lds[128 * 32];
    __shared__ __align__(16) unsigned short B_lds[128 * 32];
    const int par = blockIdx.y, py = par >> 1, px = par & 1;
    const int s0 = blockIdx.x * 128;
    const int bimg = s0 >> 12;
    const int oy0 = (s0 >> 6) & 63;
    const int tid = threadIdx.x;
    const int lane = tid & 63, wave = tid >> 6;
    const int wm = wave >> 1, wn = wave & 1;
    const float* xb = x + bimg * (NCI * HIN * HIN);
    f32x4 acc[4][4];
    #pragma unroll
    for (int i = 0; i < 4; ++i)
        #pragma unroll
        for (int j = 0; j < 4; ++j)
            acc[i][j] = (f32x4){0.f, 0.f, 0.f, 0.f};
    for (int kt = 0; kt < 16; ++kt) {
        const int tap = kt >> 2, ci0 = (kt & 3) * 32;
        const int ty = tap >> 1, tx = tap & 1;
        #pragma unroll
        for (int i = 0; i < 2; ++i) {
            int c = i * 256 + tid;
            *(bf16x8*)(&A_lds[c * 8]) = *(const bf16x8*)(Aw +
                ((par * 128 + (c >> 2)) * 512 + kt * 32 + (c & 3) * 8));
        }
        #pragma unroll
        for (int i = 0; i < 2; ++i) {
            int tsk = i * 256 + tid;
            int n = tsk & 127, kg = tsk >> 7;
            int r = n >> 6, ox = n & 63;
            int row = oy0 + r - 1 + py + ty;
            int col = ox - 1 + px + tx;
            bool ok = (row >= 0) & (row < HIN) & (col >= 0) & (col < HIN);
            const float* xp = xb + (((ci0 + kg * 8) * HIN + row) * HIN + col);
            bf16x8 v;
            #pragma unroll
            for (int q = 0; q < 8; ++q) {
                float f = ok ? xp[q * (HIN * HIN)] : 0.f;
                v[q] = (short)f32_to_bf16(f);
            }
            *(bf16x8*)(&B_lds[n * 32 + kg * 8]) = v;
        }
        __syncthreads();
        const int seg = (lane >> 4) * 8, rl2 = lane & 15;
        bf16x8 af[4], bfr[4];
        #pragma unroll
        for (int f = 0; f < 4; ++f)
            af[f] = *(const bf16x8*)(&A_lds[(wm * 64 + f * 16 + rl2) * 32 + seg]);
        #pragma unroll
        for (int f = 0; f < 4; ++f)
            bfr[f] = *(const bf16x8*)(&B_lds[(wn * 64 + f * 16 + rl2) * 32 + seg]);
        #pragma unroll
        for (int fm = 0; fm < 4; ++fm)
            #pragma unroll
            for (int fn = 0; fn < 4; ++fn)
                acc[fm][fn] = __builtin_amdgcn_mfma_f32_16x16x32_bf16(
                    af[fm], bfr[fn], acc[fm][fn], 0, 0, 0);
        __syncthreads();
    }
    #pragma unroll
    for (int fm = 0; fm < 4; ++fm) {
        const int co_b = wm * 64 + fm * 16 + (lane >> 4) * 4;
        float bias4[4];
        #pragma unroll
        for (int j = 0; j < 4; ++j) bias4[j] = bv[co_b + j];
        #pragma unroll
        for (int fn = 0; fn < 4; ++fn) {
            int n = wn * 64 + fn * 16 + (lane & 15);
            int s = s0 + n;
            int ox = s & 63, oy = (s >> 6) & 63, bi2 = s >> 12;
            int yy = 2 * oy + py, xx = 2 * ox + px;
            float* op = out + ((size_t)bi2 * 128 * 128 * 128) + (size_t)yy * 128 + xx;
            #pragma unroll
            for (int j = 0; j < 4; ++j)
                op[(size_t)(co_b + j) * (128 * 128)] = acc[fm][fn][j] + bias4[j];
        }
    }
}

extern "C" void kernel_launch(void* const* d_in, const int* in_sizes, int n_in,
                              void* d_out, int out_size, void* d_ws, size_t ws_size,
                              hipStream_t stream) {
    const float* x  = (const float*)d_in[0];
    const float* W  = (const float*)d_in[1];
    const float* bv = (const float*)d_in[2];
    float* out = (float*)d_out;
    unsigned short* Aw = (unsigned short*)d_ws;               // 512 KB
    const size_t aw_bytes = (size_t)4 * 16 * 2 * 2048 * sizeof(unsigned short);
    const size_t xq_bytes = (size_t)NB * 4 * HP * HP * 32 * sizeof(unsigned short);

    if (ws_size >= aw_bytes + xq_bytes) {
        unsigned short* xq = (unsigned short*)((char*)d_ws + aw_bytes);
        prep_kernel<<<1024 + NB * HP, 256, 0, stream>>>(W, x, Aw, xq);
        upconv11_kernel<<<512, 256, 0, stream>>>(xq, Aw, bv, out);
    } else {
        weff_flat_kernel<<<1024, 256, 0, stream>>>(W, Aw);
        upconv_fb_kernel<<<dim3(256, 4), 256, 0, stream>>>(x, Aw, bv, out);
    }
}

// Round 11
// 47.160 us; speedup vs baseline: 1.0201x; 1.0043x over previous
//
#include <hip/hip_runtime.h>
#include <stdint.h>

typedef short bf16x8 __attribute__((ext_vector_type(8)));
typedef float f32x4 __attribute__((ext_vector_type(4)));

#define NCI 128
#define NCO 128
#define HIN 64
#define HP  66
#define NB  8

__device__ __forceinline__ unsigned short f32_to_bf16(float f) {
    union { float f; uint32_t u; } v; v.f = f;
    return (unsigned short)((v.u + 0x7FFFu + ((v.u >> 16) & 1u)) >> 16);
}

// Effective 2x2-tap weight for parity (py,px), tap (ty,tx)
__device__ __forceinline__ float weff_sum(const float* wp, int py, int px, int ty, int tx) {
    float s = 0.f;
    #pragma unroll
    for (int ky = 0; ky < 3; ++ky) {
        bool iy = (py == 0) ? (ty == 0 ? (ky == 0) : (ky >= 1))
                            : (ty == 0 ? (ky <= 1) : (ky == 2));
        if (!iy) continue;
        #pragma unroll
        for (int kx = 0; kx < 3; ++kx) {
            bool ix = (px == 0) ? (tx == 0 ? (kx == 0) : (kx >= 1))
                                : (tx == 0 ? (kx <= 1) : (kx == 2));
            if (ix) s += wp[ky * 3 + kx];
        }
    }
    return s;
}

// ---- fused prologue (unchanged layouts) ----
// blocks [0,1024): Weff -> Aw5: offset ((par*16+kt)*2+wm)*2048 + f*512 + pl*128 + rl*8 + e
//   content = Weff[par][co = wm*64+f*16+rl][k = kt*32+pl*8+e]   (512 KB)
// blocks [1024,1552): x -> xq [8][4][66][66][32] bf16 (ci-chunked NHWC, halo included).
__global__ __launch_bounds__(256) void prep_kernel(
        const float* __restrict__ W, const float* __restrict__ x,
        unsigned short* __restrict__ Aw5, unsigned short* __restrict__ xq) {
    if (blockIdx.x < 1024) {
        int idx = blockIdx.x * 256 + threadIdx.x;     // 262144 total
        int e   = idx & 7;
        int rl  = (idx >> 3) & 15;
        int pl  = (idx >> 7) & 3;
        int f   = (idx >> 9) & 3;
        int wm  = (idx >> 11) & 1;
        int kt  = (idx >> 12) & 15;
        int par = idx >> 16;
        int co = wm * 64 + f * 16 + rl;
        int k  = kt * 32 + pl * 8 + e;
        int tap = k >> 7, ci = k & 127;
        Aw5[idx] = f32_to_bf16(weff_sum(W + (co * NCI + ci) * 9,
                                        par >> 1, par & 1, tap >> 1, tap & 1));
    } else {
        const int bb = blockIdx.x - 1024;             // 528 blocks
        const int b = bb / HP, hp = bb % HP;
        const int t = threadIdx.x;
        if (hp == 0 || hp == HP - 1) {
            bf16x8 z = (bf16x8){0, 0, 0, 0, 0, 0, 0, 0};
            for (int i = t; i < 4 * HP * 4; i += 256) {
                int g = i / (HP * 4), rem = i % (HP * 4);
                unsigned short* dst = xq +
                    ((((size_t)(b * 4 + g) * HP + hp) * HP) << 5) + rem * 8;
                *(bf16x8*)dst = z;
            }
            return;
        }
        const int h = hp - 1;
        if (t < 32) {                                  // column halo wp = 0, 65
            bf16x8 z = (bf16x8){0, 0, 0, 0, 0, 0, 0, 0};
            int g = t >> 3, wpc = ((t >> 2) & 1) * (HP - 1), q = t & 3;
            unsigned short* dst = xq +
                ((((size_t)(b * 4 + g) * HP + hp) * HP + wpc) << 5) + q * 8;
            *(bf16x8*)dst = z;
        }
        const int w = t & 63, g = t >> 6;
        const float* src = x + ((size_t)(b * NCI + g * 32) * (HIN * HIN)) + h * HIN + w;
        unsigned short* dst = xq +
            ((((size_t)(b * 4 + g) * HP + hp) * HP + (w + 1)) << 5);
        #pragma unroll
        for (int q = 0; q < 4; ++q) {
            bf16x8 v;
            #pragma unroll
            for (int j = 0; j < 8; ++j)
                v[j] = (short)f32_to_bf16(src[(size_t)(q * 8 + j) * (HIN * HIN)]);
            *(bf16x8*)(dst + q * 8) = v;
        }
    }
}

// Main GEMM: NO LDS, NO barriers. Each wave = 64co x 64sp (one ox-row) for one
// (py,px) parity. A and B both stream global(L2)->reg as contiguous 1KB
// wave-lines (B frag in xq: rl*64B + pl*16B = contiguous). B 1-ahead ping-pong
// via counted vmcnt(4); A blocking (L2-hot). 256 thr = 4 independent waves
// (pxw x wm). ~124 regs -> 4 waves/SIMD, 16 waves/CU.
__global__ __launch_bounds__(256, 4) void upconv12_kernel(
        const unsigned short* __restrict__ xq, const unsigned short* __restrict__ Aw5,
        const float* __restrict__ bv, float* __restrict__ out) {
    const int d = blockIdx.x;
    const int dsw = (d & 7) * 128 + (d >> 3);    // bijective XCD swizzle (1024%8==0)
    const int py = dsw & 1;
    const int t = dsw >> 1;                      // 0..511
    const int bi = t >> 6;
    const int oy0 = t & 63;
    const int tid = threadIdx.x, lane = tid & 63, wv = tid >> 6;
    const int pxw = wv & 1, wm = wv >> 1;
    const int rl = lane & 15, pl = lane >> 4;
    const int par = py * 2 + pxw;

    // A: lane-linear 1KB lines. per-kt stride = 4096 shorts.
    const unsigned short* Ab = Aw5 + ((par * 16 * 2 + wm) << 11) + lane * 8;
    // B: per-lane offset inside a frag line (bytes)
    const char* xqb = (const char*)xq + (((size_t)bi * 4 * HP * HP) << 6);
    const int blane = rl * 64 + pl * 16;

    f32x4 acc[4][4];
    #pragma unroll
    for (int i = 0; i < 4; ++i)
        #pragma unroll
        for (int j = 0; j < 4; ++j)
            acc[i][j] = (f32x4){0.f, 0.f, 0.f, 0.f};

    bf16x8 A0[4], B0[4], B1[4];

    auto loadA = [&](int kt) {
        const unsigned short* p = Ab + (kt << 12);
        #pragma unroll
        for (int f = 0; f < 4; ++f)
            A0[f] = *(const bf16x8*)(p + f * 512);
    };
    auto loadB = [&](bf16x8* Bd, int kt) {
        const int row = oy0 + py + (kt >> 3);
        const int g = kt & 3;
        const int cb = pxw + ((kt >> 2) & 1);
        const char* base = xqb + (((g * HP + row) * HP + cb) << 6) + blane;
        #pragma unroll
        for (int fn = 0; fn < 4; ++fn)
            Bd[fn] = *(const bf16x8*)(base + fn * 1024);
    };

    #define MFMA_STEP(BB)                                                     \
        __builtin_amdgcn_s_setprio(1);                                        \
        _Pragma("unroll")                                                     \
        for (int fn = 0; fn < 4; ++fn) {                                      \
            _Pragma("unroll")                                                 \
            for (int fm = 0; fm < 4; ++fm)                                    \
                acc[fm][fn] = __builtin_amdgcn_mfma_f32_16x16x32_bf16(        \
                    A0[fm], BB[fn], acc[fm][fn], 0, 0, 0);                    \
        }                                                                     \
        __builtin_amdgcn_s_setprio(0);

    loadB(B0, 0);
    for (int kp = 0; kp < 8; ++kp) {
        int kt = kp * 2;
        loadA(kt);
        loadB(B1, kt + 1);
        asm volatile("s_waitcnt vmcnt(4)" ::: "memory");   // retire A, B(kt)
        MFMA_STEP(B0)
        kt = kp * 2 + 1;
        loadA(kt);
        if (kp < 7) {
            loadB(B0, kt + 1);
            asm volatile("s_waitcnt vmcnt(4)" ::: "memory");
        } else {
            asm volatile("s_waitcnt vmcnt(0)" ::: "memory");
        }
        MFMA_STEP(B1)
    }
    #undef MFMA_STEP

    // epilogue: direct strided stores; partner pxw-wave in same block fills the
    // complementary 4B slots -> lines merge in L2. C/D: col=lane&15 (n),
    // row=pl*4+j (co).
    const int yy = 2 * oy0 + py;
    float* ob = out + (((size_t)bi * NCO + wm * 64 + pl * 4) << 14)
                    + yy * 128 + 2 * rl + pxw;
    #pragma unroll
    for (int fm = 0; fm < 4; ++fm) {
        #pragma unroll
        for (int j = 0; j < 4; ++j) {
            const float bb = bv[wm * 64 + fm * 16 + pl * 4 + j];
            float* o2 = ob + ((fm * 16 + j) << 14);
            #pragma unroll
            for (int fn = 0; fn < 4; ++fn)
                o2[fn * 32] = acc[fm][fn][j] + bb;
        }
    }
}

// -------- fallback (ws too small for xq): flat Weff + direct-x kernel --------
__global__ void weff_flat_kernel(const float* __restrict__ W,
                                 unsigned short* __restrict__ Aw) {
    int idx = blockIdx.x * 256 + threadIdx.x;   // Aw[par][co][512]
    int par = idx >> 16;
    int co  = (idx >> 9) & 127;
    int k   = idx & 511;
    int tap = k >> 7, ci = k & 127;
    Aw[idx] = f32_to_bf16(weff_sum(W + (co * NCI + ci) * 9,
                                   par >> 1, par & 1, tap >> 1, tap & 1));
}

__global__ __launch_bounds__(256) void upconv_fb_kernel(
        const float* __restrict__ x, const unsigned short* __restrict__ Aw,
        const float* __restrict__ bv, float* __restrict__ out) {
    __shared__ __align__(16) unsigned short A_lds[128 * 32];
    __shared__ __align__(16) unsigned short B_lds[128 * 32];
    const int par = blockIdx.y, py = par >> 1, px = par & 1;
    const int s0 = blockIdx.x * 128;
    const int bimg = s0 >> 12;
    const int oy0 = (s0 >> 6) & 63;
    const int tid = threadIdx.x;
    const int lane = tid & 63, wave = tid >> 6;
    const int wm = wave >> 1, wn = wave & 1;
    const float* xb = x + bimg * (NCI * HIN * HIN);
    f32x4 acc[4][4];
    #pragma unroll
    for (int i = 0; i < 4; ++i)
        #pragma unroll
        for (int j = 0; j < 4; ++j)
            acc[i][j] = (f32x4){0.f, 0.f, 0.f, 0.f};
    for (int kt = 0; kt < 16; ++kt) {
        const int tap = kt >> 2, ci0 = (kt & 3) * 32;
        const int ty = tap >> 1, tx = tap & 1;
        #pragma unroll
        for (int i = 0; i < 2; ++i) {
            int c = i * 256 + tid;
            *(bf16x8*)(&A_lds[c * 8]) = *(const bf16x8*)(Aw +
                ((par * 128 + (c >> 2)) * 512 + kt * 32 + (c & 3) * 8));
        }
        #pragma unroll
        for (int i = 0; i < 2; ++i) {
            int tsk = i * 256 + tid;
            int n = tsk & 127, kg = tsk >> 7;
            int r = n >> 6, ox = n & 63;
            int row = oy0 + r - 1 + py + ty;
            int col = ox - 1 + px + tx;
            bool ok = (row >= 0) & (row < HIN) & (col >= 0) & (col < HIN);
            const float* xp = xb + (((ci0 + kg * 8) * HIN + row) * HIN + col);
            bf16x8 v;
            #pragma unroll
            for (int q = 0; q < 8; ++q) {
                float f = ok ? xp[q * (HIN * HIN)] : 0.f;
                v[q] = (short)f32_to_bf16(f);
            }
            *(bf16x8*)(&B_lds[n * 32 + kg * 8]) = v;
        }
        __syncthreads();
        const int seg = (lane >> 4) * 8, rl2 = lane & 15;
        bf16x8 af[4], bfr[4];
        #pragma unroll
        for (int f = 0; f < 4; ++f)
            af[f] = *(const bf16x8*)(&A_lds[(wm * 64 + f * 16 + rl2) * 32 + seg]);
        #pragma unroll
        for (int f = 0; f < 4; ++f)
            bfr[f] = *(const bf16x8*)(&B_lds[(wn * 64 + f * 16 + rl2) * 32 + seg]);
        #pragma unroll
        for (int fm = 0; fm < 4; ++fm)
            #pragma unroll
            for (int fn = 0; fn < 4; ++fn)
                acc[fm][fn] = __builtin_amdgcn_mfma_f32_16x16x32_bf16(
                    af[fm], bfr[fn], acc[fm][fn], 0, 0, 0);
        __syncthreads();
    }
    #pragma unroll
    for (int fm = 0; fm < 4; ++fm) {
        const int co_b = wm * 64 + fm * 16 + (lane >> 4) * 4;
        float bias4[4];
        #pragma unroll
        for (int j = 0; j < 4; ++j) bias4[j] = bv[co_b + j];
        #pragma unroll
        for (int fn = 0; fn < 4; ++fn) {
            int n = wn * 64 + fn * 16 + (lane & 15);
            int s = s0 + n;
            int ox = s & 63, oy = (s >> 6) & 63, bi2 = s >> 12;
            int yy = 2 * oy + py, xx = 2 * ox + px;
            float* op = out + ((size_t)bi2 * 128 * 128 * 128) + (size_t)yy * 128 + xx;
            #pragma unroll
            for (int j = 0; j < 4; ++j)
                op[(size_t)(co_b + j) * (128 * 128)] = acc[fm][fn][j] + bias4[j];
        }
    }
}

extern "C" void kernel_launch(void* const* d_in, const int* in_sizes, int n_in,
                              void* d_out, int out_size, void* d_ws, size_t ws_size,
                              hipStream_t stream) {
    const float* x  = (const float*)d_in[0];
    const float* W  = (const float*)d_in[1];
    const float* bv = (const float*)d_in[2];
    float* out = (float*)d_out;
    unsigned short* Aw = (unsigned short*)d_ws;               // 512 KB
    const size_t aw_bytes = (size_t)4 * 16 * 2 * 2048 * sizeof(unsigned short);
    const size_t xq_bytes = (size_t)NB * 4 * HP * HP * 32 * sizeof(unsigned short);

    if (ws_size >= aw_bytes + xq_bytes) {
        unsigned short* xq = (unsigned short*)((char*)d_ws + aw_bytes);
        prep_kernel<<<1024 + NB * HP, 256, 0, stream>>>(W, x, Aw, xq);
        upconv12_kernel<<<1024, 256, 0, stream>>>(xq, Aw, bv, out);
    } else {
        weff_flat_kernel<<<1024, 256, 0, stream>>>(W, Aw);
        upconv_fb_kernel<<<dim3(256, 4), 256, 0, stream>>>(x, Aw, bv, out);
    }
}